// Round 6
// baseline (444.211 us; speedup 1.0000x reference)
//
#include <hip/hip_runtime.h>
#include <math.h>

#define GDIM 152
#define NA 3
#define GG (GDIM * GDIM)        // 23104
#define EXP_CLAMP 1000.0f
#define NTHREADS 256
#define CPT 8                   // cells per thread; 8 | GG and 8 | GDIM -> same plane, same row
#define CPB (NTHREADS * CPT)    // 2048 cells per block
#define NBLK (32 * NA * GG / CPB)   // 2,217,984 / 2048 = 1083, exact

typedef float floatx4 __attribute__((ext_vector_type(4)));

__device__ __forceinline__ float sigmoidf(float v) {
    return 1.0f / (1.0f + __expf(-v));
}

// No LDS, no barriers. Each thread owns 8 contiguous cells = 384 output bytes
// = exactly 6 cache lines (thread-aligned), so direct per-cell float4 stores
// fully cover whole lines: L2 byte-merge -> full-line writebacks, no transpose
// needed. 24 independent dwordx4 loads issued upfront (96 data VGPRs) give
// 2.7x the in-flight read bytes of the LDS version (16 waves/CU x 384 B).
__global__ __launch_bounds__(NTHREADS, 4) void yolo_decode_direct(
    const float* __restrict__ x,
    const float* __restrict__ anchors,
    const int* __restrict__ img_size_p,
    float* __restrict__ out)
{
    const int T = blockIdx.x * NTHREADS + threadIdx.x;
    const int cbase = T * CPT;                       // first cell of this thread
    const unsigned t2 = (unsigned)cbase / (unsigned)GG;   // b*NA + a
    const int pos = cbase - (int)t2 * GG;            // within-plane offset
    const int gy  = pos / GDIM;
    const int gx0 = pos - gy * GDIM;                 // 8 | GDIM -> cells share the row
    const int a   = (int)(t2 % 3u);

    const float stride = (float)(*img_size_p) / (float)GDIM;   // 4.0
    const float inv_s  = 1.0f / stride;

    const floatx4* ip = (const floatx4*)x + (size_t)(t2 * 12u) * (GG / 4) + (pos >> 2);
    const int PS = GG / 4;

    // 24 independent 16B loads: r[2p] = cells 0..3 of plane p, r[2p+1] = cells 4..7.
    floatx4 r[24];
#pragma unroll
    for (int p = 0; p < 12; ++p) {
        r[2 * p]     = ip[p * PS];
        r[2 * p + 1] = ip[p * PS + 1];
    }

    const float ah = anchors[a * 5 + 0] * inv_s * stride;  // matches reference rounding
    const float aw = anchors[a * 5 + 1] * inv_s * stride;
    const float al = anchors[a * 5 + 2] * inv_s * stride;
    const float gyf = (float)gy;

    floatx4* op = (floatx4*)out + (size_t)cbase * 3;   // 3 float4 per cell, contiguous

#pragma unroll
    for (int h = 0; h < 2; ++h) {          // half h: cells 4h .. 4h+3 (reg slot 2p+h)
#pragma unroll
        for (int J = 0; J < 4; ++J) {      // all indices compile-time: stays in regs
            floatx4 o0, o1, o2;
            o0.x = (sigmoidf(r[0 * 2 + h][J]) + (float)(gx0 + 4 * h + J)) * stride;
            o0.y = (sigmoidf(r[1 * 2 + h][J]) + gyf) * stride;
            o0.z = sigmoidf(r[2 * 2 + h][J]);
            o0.w = fminf(__expf(r[3 * 2 + h][J]), EXP_CLAMP) * ah;
            o1.x = fminf(__expf(r[4 * 2 + h][J]), EXP_CLAMP) * aw;
            o1.y = fminf(__expf(r[5 * 2 + h][J]), EXP_CLAMP) * al;
            o1.z = r[6 * 2 + h][J];
            o1.w = r[7 * 2 + h][J];
            o2.x = sigmoidf(r[8 * 2 + h][J]);
            o2.y = sigmoidf(r[9 * 2 + h][J]);
            o2.z = sigmoidf(r[10 * 2 + h][J]);
            o2.w = sigmoidf(r[11 * 2 + h][J]);

            const int cell = 4 * h + J;
            __builtin_nontemporal_store(o0, op + cell * 3 + 0);
            __builtin_nontemporal_store(o1, op + cell * 3 + 1);
            __builtin_nontemporal_store(o2, op + cell * 3 + 2);
        }
    }
}

extern "C" void kernel_launch(void* const* d_in, const int* in_sizes, int n_in,
                              void* d_out, int out_size, void* d_ws, size_t ws_size,
                              hipStream_t stream) {
    const float* x        = (const float*)d_in[0];
    const float* anchors  = (const float*)d_in[1];
    const int*   img_size = (const int*)d_in[2];
    float*       out      = (float*)d_out;

    yolo_decode_direct<<<NBLK, NTHREADS, 0, stream>>>(x, anchors, img_size, out);
}

// Round 8
// 190.937 us; speedup vs baseline: 2.3265x; 2.3265x over previous
//
#include <hip/hip_runtime.h>
#include <math.h>

#define GDIM 152
#define NA 3
#define GG (GDIM * GDIM)   // 23104
#define EXP_CLAMP 1000.0f
#define NTHREADS 64        // single-wave blocks
#define TILE 128           // cells per block = 2 * NTHREADS  (halved vs baseline)
#define GSTRIDE (TILE + 1) // 129 float4s between group planes: bank-quad offset 1/group
#define NBLK (32 * NA * GG / TILE)   // 2,217,984 / 128 = 17,328, exact

typedef float floatx4 __attribute__((ext_vector_type(4)));
typedef float floatx2 __attribute__((ext_vector_type(2)));

__device__ __forceinline__ float sigmoidf(float v) {
    return 1.0f / (1.0f + __expf(-v));
}

// XOR swizzle on float4 entry index (bijective on [0,128): bits 3-5 fold into
// 0-2). Phase-1 writes entries e=2t+J: swz spreads lanes across all 8 bank
// quads (8 lanes/quad over a >=4-clock b128 ~= 2-way, free per m136).
__device__ __forceinline__ int swz(int e) { return e ^ ((e >> 3) & 7); }

// Same proven structure as the 63.5us baseline (LDS transpose -> lane-contiguous
// nt stores), tile halved to double LDS-capped occupancy: 12.3KB -> 6.2KB/block
// = 25 single-wave blocks/CU instead of 12. Per-wave serial chain also halves.
__global__ __launch_bounds__(NTHREADS) void yolo_decode_h128(
    const float* __restrict__ x,
    const float* __restrict__ anchors,
    const int* __restrict__ img_size_p,
    float* __restrict__ out)
{
    __shared__ floatx4 sh[3 * GSTRIDE];   // 6,192 B

    const int t = threadIdx.x;
    const int tilebase = blockIdx.x * TILE;   // global cell index of tile start

    const float stride = (float)(*img_size_p) / (float)GDIM;  // 4.0
    const float inv_s = 1.0f / stride;

    // This thread's 2 cells: cbase, cbase+1 (cbase even, GDIM even, GG even
    // -> same plane, same row)
    const int cbase = tilebase + 2 * t;
    const unsigned t2 = (unsigned)cbase / (unsigned)GG;  // b*NA + a
    const int pos = cbase - (int)t2 * GG;                // within-plane offset
    const int gy  = pos / GDIM;
    const int gx0 = pos - gy * GDIM;
    const int a   = (int)(t2 % 3u);
    const float gyf = (float)gy;

    const floatx2* ip = (const floatx2*)x + (size_t)(t2 * 12u) * (GG / 2) + (pos >> 1);
    const int PS = GG / 2;

    // 12 independent dwordx2 loads (lane stride 8B -> 512B contiguous/instr)
    floatx2 r0  = ip[0 * PS];
    floatx2 r1  = ip[1 * PS];
    floatx2 r2  = ip[2 * PS];
    floatx2 r3  = ip[3 * PS];
    floatx2 r4  = ip[4 * PS];
    floatx2 r5  = ip[5 * PS];
    floatx2 r6  = ip[6 * PS];
    floatx2 r7  = ip[7 * PS];
    floatx2 r8  = ip[8 * PS];
    floatx2 r9  = ip[9 * PS];
    floatx2 r10 = ip[10 * PS];
    floatx2 r11 = ip[11 * PS];

    const float ah = anchors[a * 5 + 0] * inv_s * stride;  // matches reference rounding
    const float aw = anchors[a * 5 + 1] * inv_s * stride;
    const float al = anchors[a * 5 + 2] * inv_s * stride;

#define PROC(J, C)                                                       \
    do {                                                                 \
        floatx4 o0, o1, o2;                                              \
        o0.x = (sigmoidf(r0.C) + (float)(gx0 + J)) * stride;             \
        o0.y = (sigmoidf(r1.C) + gyf) * stride;                          \
        o0.z = sigmoidf(r2.C);                                           \
        o0.w = fminf(__expf(r3.C), EXP_CLAMP) * ah;                      \
        o1.x = fminf(__expf(r4.C), EXP_CLAMP) * aw;                      \
        o1.y = fminf(__expf(r5.C), EXP_CLAMP) * al;                      \
        o1.z = r6.C;                                                     \
        o1.w = r7.C;                                                     \
        o2.x = sigmoidf(r8.C);                                           \
        o2.y = sigmoidf(r9.C);                                           \
        o2.z = sigmoidf(r10.C);                                          \
        o2.w = sigmoidf(r11.C);                                          \
        int e = swz(2 * t + (J));                                        \
        sh[0 * GSTRIDE + e] = o0;                                        \
        sh[1 * GSTRIDE + e] = o1;                                        \
        sh[2 * GSTRIDE + e] = o2;                                        \
    } while (0)

    PROC(0, x);
    PROC(1, y);
#undef PROC

    __syncthreads();   // single wave: cheap drain

    // Phase 2: lane-contiguous nontemporal stores. Tile output = 384 float4s.
    floatx4* op = (floatx4*)out + (size_t)tilebase * 3;
#pragma unroll
    for (int k = 0; k < 6; ++k) {
        int F = t + NTHREADS * k;                 // output float4 index in tile
        unsigned cell = (unsigned)F / 3u;         // cell within tile
        int g = F - (int)cell * 3;                // component group 0..2
        floatx4 v = sh[g * GSTRIDE + swz((int)cell)];
        __builtin_nontemporal_store(v, op + F);
    }
}

extern "C" void kernel_launch(void* const* d_in, const int* in_sizes, int n_in,
                              void* d_out, int out_size, void* d_ws, size_t ws_size,
                              hipStream_t stream) {
    const float* x        = (const float*)d_in[0];
    const float* anchors  = (const float*)d_in[1];
    const int*   img_size = (const int*)d_in[2];
    float*       out      = (float*)d_out;

    yolo_decode_h128<<<NBLK, NTHREADS, 0, stream>>>(x, anchors, img_size, out);
}

// Round 11
// 189.644 us; speedup vs baseline: 2.3423x; 1.0068x over previous
//
#include <hip/hip_runtime.h>
#include <math.h>

#define GDIM 152
#define NA 3
#define GG (GDIM * GDIM)   // 23104
#define EXP_CLAMP 1000.0f
#define NTHREADS 64        // single-wave blocks
#define TILE 128           // cells per block = 2 * NTHREADS
#define GSTRIDE (TILE + 1) // 129 float4s between group planes: bank-quad offset 1/group
#define NBLK (32 * NA * GG / TILE)   // 2,217,984 / 128 = 17,328, exact

typedef float floatx4 __attribute__((ext_vector_type(4)));
typedef float floatx2 __attribute__((ext_vector_type(2)));

__device__ __forceinline__ float sigmoidf(float v) {
    return 1.0f / (1.0f + __expf(-v));
}

// XOR swizzle on float4 entry index (bijective on [0,128)).
__device__ __forceinline__ int swz(int e) { return e ^ ((e >> 3) & 7); }

// A/B vs Round-8's measured kernel: ONE variable flipped — nontemporal store
// hint removed. Theory: NT stores bypass L2 and are write-ack-latency-bound at
// ~1.6 TB/s chip-wide (per-CU outstanding-store limit x HBM ack latency),
// which matched the measured wall in every prior variant regardless of
// occupancy. Plain stores complete at L2 (34.5 TB/s, ~100cy ack); L2 drains
// to HBM asynchronously (harness fill: 6.7 TB/s at 9% occupancy, plain stores).
__global__ __launch_bounds__(NTHREADS) void yolo_decode_h128p(
    const float* __restrict__ x,
    const float* __restrict__ anchors,
    const int* __restrict__ img_size_p,
    float* __restrict__ out)
{
    __shared__ floatx4 sh[3 * GSTRIDE];   // 6,192 B -> ~25 single-wave blocks/CU

    const int t = threadIdx.x;
    const int tilebase = blockIdx.x * TILE;   // global cell index of tile start

    const float stride = (float)(*img_size_p) / (float)GDIM;  // 4.0
    const float inv_s = 1.0f / stride;

    // This thread's 2 cells: cbase, cbase+1 (same plane, same row)
    const int cbase = tilebase + 2 * t;
    const unsigned t2 = (unsigned)cbase / (unsigned)GG;  // b*NA + a
    const int pos = cbase - (int)t2 * GG;                // within-plane offset
    const int gy  = pos / GDIM;
    const int gx0 = pos - gy * GDIM;
    const int a   = (int)(t2 % 3u);
    const float gyf = (float)gy;

    const floatx2* ip = (const floatx2*)x + (size_t)(t2 * 12u) * (GG / 2) + (pos >> 1);
    const int PS = GG / 2;

    // 12 independent dwordx2 loads (lane stride 8B -> 512B contiguous/instr)
    floatx2 r0  = ip[0 * PS];
    floatx2 r1  = ip[1 * PS];
    floatx2 r2  = ip[2 * PS];
    floatx2 r3  = ip[3 * PS];
    floatx2 r4  = ip[4 * PS];
    floatx2 r5  = ip[5 * PS];
    floatx2 r6  = ip[6 * PS];
    floatx2 r7  = ip[7 * PS];
    floatx2 r8  = ip[8 * PS];
    floatx2 r9  = ip[9 * PS];
    floatx2 r10 = ip[10 * PS];
    floatx2 r11 = ip[11 * PS];

    const float ah = anchors[a * 5 + 0] * inv_s * stride;  // matches reference rounding
    const float aw = anchors[a * 5 + 1] * inv_s * stride;
    const float al = anchors[a * 5 + 2] * inv_s * stride;

#define PROC(J, C)                                                       \
    do {                                                                 \
        floatx4 o0, o1, o2;                                              \
        o0.x = (sigmoidf(r0.C) + (float)(gx0 + J)) * stride;             \
        o0.y = (sigmoidf(r1.C) + gyf) * stride;                          \
        o0.z = sigmoidf(r2.C);                                           \
        o0.w = fminf(__expf(r3.C), EXP_CLAMP) * ah;                      \
        o1.x = fminf(__expf(r4.C), EXP_CLAMP) * aw;                      \
        o1.y = fminf(__expf(r5.C), EXP_CLAMP) * al;                      \
        o1.z = r6.C;                                                     \
        o1.w = r7.C;                                                     \
        o2.x = sigmoidf(r8.C);                                           \
        o2.y = sigmoidf(r9.C);                                           \
        o2.z = sigmoidf(r10.C);                                          \
        o2.w = sigmoidf(r11.C);                                          \
        int e = swz(2 * t + (J));                                        \
        sh[0 * GSTRIDE + e] = o0;                                        \
        sh[1 * GSTRIDE + e] = o1;                                        \
        sh[2 * GSTRIDE + e] = o2;                                        \
    } while (0)

    PROC(0, x);
    PROC(1, y);
#undef PROC

    __syncthreads();   // single wave: cheap drain

    // Phase 2: lane-contiguous PLAIN stores (complete at L2, async writeback).
    floatx4* op = (floatx4*)out + (size_t)tilebase * 3;
#pragma unroll
    for (int k = 0; k < 6; ++k) {
        int F = t + NTHREADS * k;                 // output float4 index in tile
        unsigned cell = (unsigned)F / 3u;         // cell within tile
        int g = F - (int)cell * 3;                // component group 0..2
        floatx4 v = sh[g * GSTRIDE + swz((int)cell)];
        op[F] = v;                                // <-- the ONE change vs Round 8
    }
}

extern "C" void kernel_launch(void* const* d_in, const int* in_sizes, int n_in,
                              void* d_out, int out_size, void* d_ws, size_t ws_size,
                              hipStream_t stream) {
    const float* x        = (const float*)d_in[0];
    const float* anchors  = (const float*)d_in[1];
    const int*   img_size = (const int*)d_in[2];
    float*       out      = (float*)d_out;

    yolo_decode_h128p<<<NBLK, NTHREADS, 0, stream>>>(x, anchors, img_size, out);
}